// Round 13
// baseline (171.222 us; speedup 1.0000x reference)
//
#include <hip/hip_runtime.h>
#include <hip/hip_bf16.h>
#include <math.h>

// Problem constants (B=1)
#define S_LEN 2048
#define D_DIM 512
#define H_NUM 8
#define HD    64
#define C_NUM 32
#define TOPK  5
#define SCALE 0.125f   // hd^-0.5
#define QCAP  1024     // fixed qlist capacity per (h,c); load is ~320
#define ATILES 16      // query tiles per (h,c); empties exit fast

typedef __attribute__((ext_vector_type(8))) short bf16x8;   // 8 bf16 (4 VGPRs)
typedef __attribute__((ext_vector_type(4))) float f32x4;

__device__ __forceinline__ unsigned short f2b(float f) {
    __hip_bfloat16 h = __float2bfloat16(f);
    unsigned short u;
    __builtin_memcpy(&u, &h, 2);
    return u;
}
__device__ __forceinline__ bf16x8 pack8(float4 a, float4 b) {
    bf16x8 r;
    r[0] = (short)f2b(a.x); r[1] = (short)f2b(a.y);
    r[2] = (short)f2b(a.z); r[3] = (short)f2b(a.w);
    r[4] = (short)f2b(b.x); r[5] = (short)f2b(b.y);
    r[6] = (short)f2b(b.z); r[7] = (short)f2b(b.w);
    return r;
}
__device__ __forceinline__ float b2f(unsigned short u) {
    __hip_bfloat16 h;
    __builtin_memcpy(&h, &u, 2);
    return __bfloat162float(h);
}

// ---------------------------------------------------------------------------
// fp32 GEMM body (UNCHANGED — Q/K must stay byte-identical: routing top-5
// near-ties flip under any fp32 reordering; a flip costs ~1e-2 absmax).
// ---------------------------------------------------------------------------
#define BM 64
#define BN 64
#define BK 32

__device__ __forceinline__ void gemm_body(const float* __restrict__ A,
                                          const float* __restrict__ B,
                                          float* __restrict__ C,
                                          int M, int N, int K,
                                          int bx, int by) {
    __shared__ float As[BK][BM + 4];
    __shared__ float Bs[BK][BN];

    const int t  = threadIdx.x;
    const int tx = t & 15;
    const int ty = t >> 4;
    const int m0 = by * BM;
    const int n0 = bx * BN;

    float4 acc0 = make_float4(0.f,0.f,0.f,0.f);
    float4 acc1 = make_float4(0.f,0.f,0.f,0.f);
    float4 acc2 = make_float4(0.f,0.f,0.f,0.f);
    float4 acc3 = make_float4(0.f,0.f,0.f,0.f);

    const int ar = t >> 3;
    const int ac = (t & 7) * 4;
    const int br = t >> 4;
    const int bc = (t & 15) * 4;

    float4 a0, a1, b0, b1;
    auto LD = [&](int k0) {
        a0 = *(const float4*)&A[(size_t)(m0 + ar)      * K + k0 + ac];
        a1 = *(const float4*)&A[(size_t)(m0 + ar + 32) * K + k0 + ac];
        b0 = *(const float4*)&B[(size_t)(k0 + br)      * N + n0 + bc];
        b1 = *(const float4*)&B[(size_t)(k0 + br + 16) * N + n0 + bc];
    };

    LD(0);
    for (int k0 = 0; k0 < K; k0 += BK) {
        __syncthreads();
        As[ac+0][ar]    = a0.x; As[ac+1][ar]    = a0.y; As[ac+2][ar]    = a0.z; As[ac+3][ar]    = a0.w;
        As[ac+0][ar+32] = a1.x; As[ac+1][ar+32] = a1.y; As[ac+2][ar+32] = a1.z; As[ac+3][ar+32] = a1.w;
        *(float4*)&Bs[br][bc]      = b0;
        *(float4*)&Bs[br + 16][bc] = b1;
        __syncthreads();

        if (k0 + BK < K) LD(k0 + BK);

        #pragma unroll
        for (int kk = 0; kk < BK; ++kk) {
            float4 a = *(const float4*)&As[kk][ty * 4];
            float4 b = *(const float4*)&Bs[kk][tx * 4];
            acc0.x += a.x*b.x; acc0.y += a.x*b.y; acc0.z += a.x*b.z; acc0.w += a.x*b.w;
            acc1.x += a.y*b.x; acc1.y += a.y*b.y; acc1.z += a.y*b.z; acc1.w += a.y*b.w;
            acc2.x += a.z*b.x; acc2.y += a.z*b.y; acc2.z += a.z*b.z; acc2.w += a.z*b.w;
            acc3.x += a.w*b.x; acc3.y += a.w*b.y; acc3.z += a.w*b.z; acc3.w += a.w*b.w;
        }
    }

    *(float4*)&C[(size_t)(m0 + ty*4 + 0) * N + n0 + tx*4] = acc0;
    *(float4*)&C[(size_t)(m0 + ty*4 + 1) * N + n0 + tx*4] = acc1;
    *(float4*)&C[(size_t)(m0 + ty*4 + 2) * N + n0 + tx*4] = acc2;
    *(float4*)&C[(size_t)(m0 + ty*4 + 3) * N + n0 + tx*4] = acc3;
}

// ---------------------------------------------------------------------------
// bf16 MFMA GEMM body for the V projection (fp32 A, fp32 B, bf16 C).
// Fragments per R11-verified layouts.
// ---------------------------------------------------------------------------
__device__ __forceinline__ void gemm_v_body(const float* __restrict__ A,
                                            const float* __restrict__ B,
                                            unsigned short* __restrict__ C,
                                            int M, int N, int K,
                                            int bx, int by) {
    __shared__ unsigned short Asv[64][72];
    __shared__ unsigned short Bsv[64][72];

    const int t  = threadIdx.x;
    const int m0 = by * 64;
    const int n0 = bx * 64;
    const int rl = t >> 2;
    const int c4 = (t & 3) * 16;

    const int lane = t & 63, w = t >> 6, lr = lane & 15, quad = lane >> 4;

    f32x4 acc[4] = {{0.f,0.f,0.f,0.f},{0.f,0.f,0.f,0.f},
                    {0.f,0.f,0.f,0.f},{0.f,0.f,0.f,0.f}};

    float4 fa[4], fb[4];
    auto LDA = [&](int k0) {
        const float* p = &A[(size_t)(m0 + rl) * K + k0 + c4];
        fa[0] = *(const float4*)&p[0];  fa[1] = *(const float4*)&p[4];
        fa[2] = *(const float4*)&p[8];  fa[3] = *(const float4*)&p[12];
    };
    auto LDB = [&](int k0) {
        const float* p = &B[(size_t)(k0 + rl) * N + n0 + c4];
        fb[0] = *(const float4*)&p[0];  fb[1] = *(const float4*)&p[4];
        fb[2] = *(const float4*)&p[8];  fb[3] = *(const float4*)&p[12];
    };

    LDA(0); LDB(0);
    for (int k0 = 0; k0 < K; k0 += 64) {
        __syncthreads();
        *(bf16x8*)&Asv[rl][c4]     = pack8(fa[0], fa[1]);
        *(bf16x8*)&Asv[rl][c4 + 8] = pack8(fa[2], fa[3]);
        #pragma unroll
        for (int f = 0; f < 4; ++f) {   // B transpose: Bsv[n][k]
            float4 v = fb[f];
            Bsv[c4 + f*4 + 0][rl] = f2b(v.x);
            Bsv[c4 + f*4 + 1][rl] = f2b(v.y);
            Bsv[c4 + f*4 + 2][rl] = f2b(v.z);
            Bsv[c4 + f*4 + 3][rl] = f2b(v.w);
        }
        __syncthreads();

        if (k0 + 64 < K) { LDA(k0 + 64); LDB(k0 + 64); }

        bf16x8 a0 = *(const bf16x8*)&Asv[w * 16 + lr][quad * 8];
        bf16x8 a1 = *(const bf16x8*)&Asv[w * 16 + lr][32 + quad * 8];
        #pragma unroll
        for (int nt = 0; nt < 4; ++nt) {
            bf16x8 b0 = *(const bf16x8*)&Bsv[nt * 16 + lr][quad * 8];
            bf16x8 b1 = *(const bf16x8*)&Bsv[nt * 16 + lr][32 + quad * 8];
            acc[nt] = __builtin_amdgcn_mfma_f32_16x16x32_bf16(a0, b0, acc[nt], 0, 0, 0);
            acc[nt] = __builtin_amdgcn_mfma_f32_16x16x32_bf16(a1, b1, acc[nt], 0, 0, 0);
        }
    }

    #pragma unroll
    for (int nt = 0; nt < 4; ++nt)
        #pragma unroll
        for (int r = 0; r < 4; ++r) {
            int m = m0 + w * 16 + quad * 4 + r;
            int n = n0 + nt * 16 + lr;
            C[(size_t)m * N + n] = f2b(acc[nt][r]);
        }
}

// ---------------------------------------------------------------------------
// Fused projections: z=0 -> Q (fp32), z=1 -> K (fp32), z=2 -> V (bf16 MFMA).
// z=2 block (0,0) also zeroes the routing counters. One dispatch, V work
// overlaps Q/K across blocks. Q/K math byte-identical to round 12.
// ---------------------------------------------------------------------------
__global__ __launch_bounds__(256) void gemm_qkvz(const float* __restrict__ x,
                                                 const float* __restrict__ Wq,
                                                 const float* __restrict__ Wk,
                                                 const float* __restrict__ Wv,
                                                 float* __restrict__ Qb,
                                                 float* __restrict__ Kb,
                                                 unsigned short* __restrict__ Vbf,
                                                 int* __restrict__ cur) {
    if (blockIdx.z == 2) {
        if (blockIdx.x == 0 && blockIdx.y == 0) cur[threadIdx.x] = 0;
        gemm_v_body(x, Wv, Vbf, S_LEN, D_DIM, D_DIM, blockIdx.x, blockIdx.y);
    } else {
        const float* B = (blockIdx.z == 0) ? Wq : Wk;
        float*       C = (blockIdx.z == 0) ? Qb : Kb;
        gemm_body(x, B, C, S_LEN, D_DIM, D_DIM, blockIdx.x, blockIdx.y);
    }
}

// ---------------------------------------------------------------------------
// chunk_keys[c][dcol] = mean over 64 rows of K (fp32 — feeds routing).
// ---------------------------------------------------------------------------
__global__ __launch_bounds__(256) void chunk_keys_kernel(const float* __restrict__ K,
                                                         float* __restrict__ ck) {
    int i = blockIdx.x * 256 + threadIdx.x;
    int c = i >> 9;
    int d = i & 511;
    const float* p = K + (size_t)c * 64 * D_DIM + d;
    float sum = 0.f;
    #pragma unroll
    for (int r = 0; r < 64; ++r) sum += p[(size_t)r * D_DIM];
    ck[(size_t)c * D_DIM + d] = sum * (1.0f / 64.0f);
}

// ---------------------------------------------------------------------------
// Fused sims + top-5 + scatter (fp32, unchanged — routing-faithful).
// ---------------------------------------------------------------------------
__global__ __launch_bounds__(256) void sims_topk(const float* __restrict__ Q,
                                                 const float* __restrict__ ck,
                                                 int* __restrict__ cur,
                                                 unsigned short* __restrict__ qlist) {
    __shared__ float qtile[64][68];
    __shared__ float cks[32][68];
    __shared__ float simsb[64][36];
    __shared__ int   lds_cnt[32];
    __shared__ int   lds_base[32];

    const int t  = threadIdx.x;
    const int s0 = blockIdx.x * 64;
    const int h  = blockIdx.y;

    if (t < 32) lds_cnt[t] = 0;

    {
        int r = t >> 2;
        #pragma unroll
        for (int i = 0; i < 4; ++i) {
            int cf4 = (t & 3) * 4 + i;
            *(float4*)&qtile[r][cf4 * 4] =
                *(const float4*)&Q[(size_t)(s0 + r) * D_DIM + h * HD + cf4 * 4];
        }
    }
    for (int i = t; i < C_NUM * 16; i += 256) {
        int c = i >> 4, df4 = i & 15;
        *(float4*)&cks[c][df4 * 4] =
            *(const float4*)&ck[(size_t)c * D_DIM + h * HD + df4 * 4];
    }
    __syncthreads();

    {
        const int sl = t >> 2, g = t & 3;
        float sa[8] = {0.f,0.f,0.f,0.f,0.f,0.f,0.f,0.f};
        #pragma unroll
        for (int d4 = 0; d4 < 16; ++d4) {
            float4 q4 = *(const float4*)&qtile[sl][d4 * 4];
            #pragma unroll
            for (int j = 0; j < 8; ++j) {
                float4 c4 = *(const float4*)&cks[g * 8 + j][d4 * 4];
                sa[j] += q4.x*c4.x + q4.y*c4.y + q4.z*c4.z + q4.w*c4.w;
            }
        }
        *(float4*)&simsb[sl][g*8 + 0] = make_float4(sa[0], sa[1], sa[2], sa[3]);
        *(float4*)&simsb[sl][g*8 + 4] = make_float4(sa[4], sa[5], sa[6], sa[7]);
    }
    __syncthreads();

    int csel[TOPK], lpos[TOPK];
    if (t < 64) {
        float sv[32];
        #pragma unroll
        for (int cq = 0; cq < 8; ++cq) {
            float4 v = *(const float4*)&simsb[t][cq * 4];
            sv[cq*4+0] = v.x; sv[cq*4+1] = v.y; sv[cq*4+2] = v.z; sv[cq*4+3] = v.w;
        }
        #pragma unroll
        for (int k = 0; k < TOPK; ++k) {
            float best = -INFINITY; int bi = 0;
            #pragma unroll
            for (int cc = 0; cc < 32; ++cc) {
                bool gt = sv[cc] > best;
                best = gt ? sv[cc] : best;
                bi   = gt ? cc : bi;
            }
            #pragma unroll
            for (int cc = 0; cc < 32; ++cc)
                if (cc == bi) sv[cc] = -INFINITY;
            csel[k] = bi;
            lpos[k] = atomicAdd(&lds_cnt[bi], 1);
        }
    }
    __syncthreads();

    if (t < 32) lds_base[t] = atomicAdd(&cur[h * 32 + t], lds_cnt[t]);
    __syncthreads();

    if (t < 64) {
        #pragma unroll
        for (int k = 0; k < TOPK; ++k) {
            int c = csel[k];
            int pos = lds_base[c] + lpos[k];
            if (pos < QCAP)
                qlist[(size_t)(h * 32 + c) * QCAP + pos] =
                    (unsigned short)((s0 + t) | (k << 11));
        }
    }
}

// ---------------------------------------------------------------------------
// MFMA chunk-centric attention (v6 — unchanged from round 12).
// ---------------------------------------------------------------------------
__global__ __launch_bounds__(256) void moc_attn6(const float* __restrict__ Q,
                                                 const float* __restrict__ K,
                                                 const unsigned short* __restrict__ Vbf,
                                                 const int* __restrict__ cnt,
                                                 const unsigned short* __restrict__ qlist,
                                                 float* __restrict__ lpart,
                                                 float* __restrict__ Opart) {
    __shared__ unsigned short Qs[64][72];
    __shared__ unsigned short Ks[64][72];
    __shared__ unsigned short VT[64][72];
    __shared__ unsigned short Ps[64][72];
    __shared__ unsigned short slist[64];

    const int hc = blockIdx.y;
    const int h  = hc >> 5;
    const int c  = hc & 31;
    const int g  = blockIdx.x;
    const int t  = threadIdx.x;

    const int count = min(cnt[hc], QCAP);
    const int base  = g * 64;
    if (base >= count) return;
    const int lim = min(count - base, 64);

    const float* Kb = K + ((size_t)c * 64) * D_DIM + h * HD;
    const unsigned short* Vb = Vbf + ((size_t)c * 64) * D_DIM + h * HD;
    const unsigned short* list = qlist + (size_t)hc * QCAP + base;

    {
        const int j  = t >> 2;
        const int d0 = (t & 3) * 16;

        const float* kr = Kb + (size_t)j * D_DIM + d0;
        float4 k0 = *(const float4*)&kr[0],  k1 = *(const float4*)&kr[4];
        float4 k2 = *(const float4*)&kr[8],  k3 = *(const float4*)&kr[12];
        *(bf16x8*)&Ks[j][d0]     = pack8(k0, k1);
        *(bf16x8*)&Ks[j][d0 + 8] = pack8(k2, k3);

        const unsigned short* vr = Vb + (size_t)j * D_DIM + d0;
        bf16x8 v0 = *(const bf16x8*)&vr[0];
        bf16x8 v1 = *(const bf16x8*)&vr[8];
        #pragma unroll
        for (int i = 0; i < 8; ++i) {
            VT[d0 + i][j]     = (unsigned short)v0[i];
            VT[d0 + 8 + i][j] = (unsigned short)v1[i];
        }

        unsigned short pv = (j < lim) ? list[j] : (unsigned short)0xFFFF;
        if ((t & 3) == 0) slist[j] = pv;
        int s = (pv == 0xFFFF) ? 0 : (int)(pv & 2047);
        const float* qr = Q + (size_t)s * D_DIM + h * HD + d0;
        float4 q0 = *(const float4*)&qr[0],  q1 = *(const float4*)&qr[4];
        float4 q2 = *(const float4*)&qr[8],  q3 = *(const float4*)&qr[12];
        *(bf16x8*)&Qs[j][d0]     = pack8(q0, q1);
        *(bf16x8*)&Qs[j][d0 + 8] = pack8(q2, q3);
    }
    __syncthreads();

    const int lane = t & 63;
    const int w    = t >> 6;
    const int lr   = lane & 15;
    const int quad = lane >> 4;

    bf16x8 aq0 = *(const bf16x8*)&Qs[w * 16 + lr][quad * 8];
    bf16x8 aq1 = *(const bf16x8*)&Qs[w * 16 + lr][32 + quad * 8];

    f32x4 acc[4];
    #pragma unroll
    for (int kt = 0; kt < 4; ++kt) {
        bf16x8 b0 = *(const bf16x8*)&Ks[kt * 16 + lr][quad * 8];
        bf16x8 b1 = *(const bf16x8*)&Ks[kt * 16 + lr][32 + quad * 8];
        f32x4 z = {0.f, 0.f, 0.f, 0.f};
        z = __builtin_amdgcn_mfma_f32_16x16x32_bf16(aq0, b0, z, 0, 0, 0);
        z = __builtin_amdgcn_mfma_f32_16x16x32_bf16(aq1, b1, z, 0, 0, 0);
        acc[kt] = z;
    }

    unsigned short pb[4][4];
    float dsum[4] = {0.f, 0.f, 0.f, 0.f};
    #pragma unroll
    for (int kt = 0; kt < 4; ++kt) {
        #pragma unroll
        for (int r = 0; r < 4; ++r) {
            unsigned short u = f2b(__expf(acc[kt][r] * SCALE));
            pb[kt][r] = u;
            dsum[r] += b2f(u);
        }
    }
    #pragma unroll
    for (int r = 0; r < 4; ++r) {
        float v = dsum[r];
        v += __shfl_xor(v, 1, 64);
        v += __shfl_xor(v, 2, 64);
        v += __shfl_xor(v, 4, 64);
        v += __shfl_xor(v, 8, 64);
        dsum[r] = v;
    }
    if (lr == 0) {
        #pragma unroll
        for (int r = 0; r < 4; ++r) {
            unsigned short sv = slist[w * 16 + quad * 4 + r];
            if (sv != 0xFFFF) {
                int kk = sv >> 11, s = sv & 2047;
                lpart[((size_t)kk * H_NUM + h) * S_LEN + s] = dsum[r];
            }
        }
    }

    #pragma unroll
    for (int kt = 0; kt < 4; ++kt)
        #pragma unroll
        for (int r = 0; r < 4; ++r)
            Ps[w * 16 + quad * 4 + r][kt * 16 + lr] = pb[kt][r];

    bf16x8 ap0 = *(const bf16x8*)&Ps[w * 16 + lr][quad * 8];
    bf16x8 ap1 = *(const bf16x8*)&Ps[w * 16 + lr][32 + quad * 8];

    #pragma unroll
    for (int dt = 0; dt < 4; ++dt) {
        bf16x8 b0 = *(const bf16x8*)&VT[dt * 16 + lr][quad * 8];
        bf16x8 b1 = *(const bf16x8*)&VT[dt * 16 + lr][32 + quad * 8];
        f32x4 z = {0.f, 0.f, 0.f, 0.f};
        z = __builtin_amdgcn_mfma_f32_16x16x32_bf16(ap0, b0, z, 0, 0, 0);
        z = __builtin_amdgcn_mfma_f32_16x16x32_bf16(ap1, b1, z, 0, 0, 0);
        #pragma unroll
        for (int r = 0; r < 4; ++r) {
            unsigned short sv = slist[w * 16 + quad * 4 + r];
            if (sv != 0xFFFF) {
                int kk = sv >> 11, s = sv & 2047;
                Opart[((((size_t)kk * H_NUM + h) * S_LEN + s) * HD) + dt * 16 + lr] = z[r];
            }
        }
    }
}

// ---------------------------------------------------------------------------
// Output projection with the partial-reduce + normalize FUSED into the
// A-load: A[m][k] = bf16( (sum_r Opart[r][h][m][d]) / (sum_r lpart[r][h][m]) )
// where h=(k)>>6, d=k&63. Same ops in the same order as the old
// reduce_norm kernel -> bit-identical A values; deletes one dispatch.
// ---------------------------------------------------------------------------
__global__ __launch_bounds__(256) void gemm_out_fused(const float* __restrict__ Opart,
                                                      const float* __restrict__ lpart,
                                                      const float* __restrict__ Wo,
                                                      float* __restrict__ out) {
    __shared__ unsigned short As[64][72];
    __shared__ unsigned short Bs[64][72];

    const int t  = threadIdx.x;
    const int m0 = blockIdx.y * 64;
    const int n0 = blockIdx.x * 64;
    const int rl = t >> 2;
    const int c4 = (t & 3) * 16;

    const int lane = t & 63, w = t >> 6, lr = lane & 15, quad = lane >> 4;
    const int N = D_DIM, K = D_DIM;

    f32x4 acc[4] = {{0.f,0.f,0.f,0.f},{0.f,0.f,0.f,0.f},
                    {0.f,0.f,0.f,0.f},{0.f,0.f,0.f,0.f}};

    float4 fa[4], fb[4];
    auto LDA = [&](int k0) {
        const int kcol = k0 + c4;
        const int h  = kcol >> 6;
        const int d0 = kcol & 63;
        const int m  = m0 + rl;
        fa[0] = make_float4(0.f,0.f,0.f,0.f);
        fa[1] = make_float4(0.f,0.f,0.f,0.f);
        fa[2] = make_float4(0.f,0.f,0.f,0.f);
        fa[3] = make_float4(0.f,0.f,0.f,0.f);
        float den = 0.f;
        #pragma unroll
        for (int r = 0; r < TOPK; ++r) {
            size_t slot = ((size_t)r * H_NUM + h) * S_LEN + m;
            const float* P = Opart + slot * HD + d0;
            float4 v0 = *(const float4*)&P[0],  v1 = *(const float4*)&P[4];
            float4 v2 = *(const float4*)&P[8],  v3 = *(const float4*)&P[12];
            fa[0].x += v0.x; fa[0].y += v0.y; fa[0].z += v0.z; fa[0].w += v0.w;
            fa[1].x += v1.x; fa[1].y += v1.y; fa[1].z += v1.z; fa[1].w += v1.w;
            fa[2].x += v2.x; fa[2].y += v2.y; fa[2].z += v2.z; fa[2].w += v2.w;
            fa[3].x += v3.x; fa[3].y += v3.y; fa[3].z += v3.z; fa[3].w += v3.w;
            den += lpart[slot];
        }
        float inv = 1.0f / den;
        #pragma unroll
        for (int f = 0; f < 4; ++f) {
            fa[f].x *= inv; fa[f].y *= inv; fa[f].z *= inv; fa[f].w *= inv;
        }
    };
    auto LDB = [&](int k0) {
        const float* p = &Wo[(size_t)(k0 + rl) * N + n0 + c4];
        fb[0] = *(const float4*)&p[0];  fb[1] = *(const float4*)&p[4];
        fb[2] = *(const float4*)&p[8];  fb[3] = *(const float4*)&p[12];
    };

    LDA(0); LDB(0);
    for (int k0 = 0; k0 < K; k0 += 64) {
        __syncthreads();
        *(bf16x8*)&As[rl][c4]     = pack8(fa[0], fa[1]);
        *(bf16x8*)&As[rl][c4 + 8] = pack8(fa[2], fa[3]);
        #pragma unroll
        for (int f = 0; f < 4; ++f) {
            float4 v = fb[f];
            Bs[c4 + f*4 + 0][rl] = f2b(v.x);
            Bs[c4 + f*4 + 1][rl] = f2b(v.y);
            Bs[c4 + f*4 + 2][rl] = f2b(v.z);
            Bs[c4 + f*4 + 3][rl] = f2b(v.w);
        }
        __syncthreads();

        if (k0 + 64 < K) { LDA(k0 + 64); LDB(k0 + 64); }

        bf16x8 a0 = *(const bf16x8*)&As[w * 16 + lr][quad * 8];
        bf16x8 a1 = *(const bf16x8*)&As[w * 16 + lr][32 + quad * 8];
        #pragma unroll
        for (int nt = 0; nt < 4; ++nt) {
            bf16x8 b0 = *(const bf16x8*)&Bs[nt * 16 + lr][quad * 8];
            bf16x8 b1 = *(const bf16x8*)&Bs[nt * 16 + lr][32 + quad * 8];
            acc[nt] = __builtin_amdgcn_mfma_f32_16x16x32_bf16(a0, b0, acc[nt], 0, 0, 0);
            acc[nt] = __builtin_amdgcn_mfma_f32_16x16x32_bf16(a1, b1, acc[nt], 0, 0, 0);
        }
    }

    #pragma unroll
    for (int nt = 0; nt < 4; ++nt)
        #pragma unroll
        for (int r = 0; r < 4; ++r) {
            int m = m0 + w * 16 + quad * 4 + r;
            int n = n0 + nt * 16 + lr;
            out[(size_t)m * N + n] = acc[nt][r];
        }
}

// ---------------------------------------------------------------------------
// Workspace: Qb 4MB | Kb 4MB | Vbf ushort 2MB | ck 64KB | lpart 320KB
//   | cur 1KB | qlist 512KB | Opart 20MB  ≈ 31 MB (layout as round 12)
// ---------------------------------------------------------------------------
extern "C" void kernel_launch(void* const* d_in, const int* in_sizes, int n_in,
                              void* d_out, int out_size, void* d_ws, size_t ws_size,
                              hipStream_t stream) {
    const float* x  = (const float*)d_in[0];
    const float* Wq = (const float*)d_in[1];
    const float* Wk = (const float*)d_in[2];
    const float* Wv = (const float*)d_in[3];
    const float* Wo = (const float*)d_in[4];
    float* out = (float*)d_out;

    const size_t SD = (size_t)S_LEN * D_DIM;
    float* ws    = (float*)d_ws;
    float* Qb    = ws;
    float* Kb    = Qb + SD;
    unsigned short* Vbf = (unsigned short*)(Kb + SD);     // [2048][512] bf16
    float* ck    = (float*)(Vbf + SD);
    float* lpart = ck + (size_t)C_NUM * D_DIM;
    int*   curb  = (int*)(lpart + (size_t)TOPK * H_NUM * S_LEN);
    unsigned short* qlst = (unsigned short*)(curb + 256);
    float* Opart = (float*)(qlst + (size_t)256 * QCAP);

    dim3 pgrid(D_DIM / 64, S_LEN / 64, 3);       // Q,K fp32 + V MFMA, one dispatch
    gemm_qkvz<<<pgrid, 256, 0, stream>>>(x, Wq, Wk, Wv, Qb, Kb, Vbf, curb);

    chunk_keys_kernel<<<(C_NUM * D_DIM) / 256, 256, 0, stream>>>(Kb, ck);

    dim3 rgrid(S_LEN / 64, H_NUM);
    sims_topk<<<rgrid, 256, 0, stream>>>(Qb, ck, curb, qlst);

    dim3 agrid(ATILES, H_NUM * C_NUM);
    moc_attn6<<<agrid, 256, 0, stream>>>(Qb, Kb, Vbf, curb, qlst, lpart, Opart);

    dim3 ogrid(D_DIM / 64, S_LEN / 64);
    gemm_out_fused<<<ogrid, 256, 0, stream>>>(Opart, lpart, Wo, out);
}